// Round 8
// baseline (553.690 us; speedup 1.0000x reference)
//
#include <hip/hip_runtime.h>
#include <stdint.h>

typedef __attribute__((ext_vector_type(8))) short short8;
typedef __attribute__((ext_vector_type(4))) float floatx4;

#define B_DIM 8192
#define K_DIM 2048
#define N_DIM 2048

// round-to-nearest-even fp32 -> bf16
__device__ __forceinline__ unsigned short f2bf(float f) {
    union { float f; unsigned u; } v; v.f = f;
    unsigned r = v.u + 0x7fffu + ((v.u >> 16) & 1u);
    return (unsigned short)(r >> 16);
}

__device__ __forceinline__ void gld_lds16(const void* g, void* l) {
    __builtin_amdgcn_global_load_lds(
        (const __attribute__((address_space(1))) void*)g,
        (__attribute__((address_space(3))) void*)l, 16, 0, 0);
}

// ---------------- prepass 1: X -> Xb (bf16), Lb = bf16(log(|x|+eps)) ----------------
__global__ __launch_bounds__(256) void prep_x(const float4* __restrict__ X4,
                                              ushort* __restrict__ Xb,
                                              ushort* __restrict__ Lb) {
    int i = blockIdx.x * 256 + threadIdx.x;
    float4 v = X4[i];
    ushort4 xb, lb;
    xb.x = f2bf(v.x); xb.y = f2bf(v.y); xb.z = f2bf(v.z); xb.w = f2bf(v.w);
    lb.x = f2bf(__logf(fabsf(v.x) + 1e-7f));
    lb.y = f2bf(__logf(fabsf(v.y) + 1e-7f));
    lb.z = f2bf(__logf(fabsf(v.z) + 1e-7f));
    lb.w = f2bf(__logf(fabsf(v.w) + 1e-7f));
    *(ushort4*)(Xb + (size_t)i * 4) = xb;
    *(ushort4*)(Lb + (size_t)i * 4) = lb;
}

// ---------------- prepass 2: Wt[n][k] = bf16(tanh(Wh)*sigmoid(Mh)), Gt[n][k] = bf16(gate) ----
__global__ __launch_bounds__(256) void prep_wg(const float* __restrict__ Wh,
                                               const float* __restrict__ Mh,
                                               const float* __restrict__ Gf,
                                               ushort* __restrict__ Wt,
                                               ushort* __restrict__ Gt) {
    __shared__ float tw[32][33];
    __shared__ float tg[32][33];
    const int k0 = blockIdx.y * 32, n0 = blockIdx.x * 32;
    const int tx = threadIdx.x, ty = threadIdx.y;  // 32 x 8
#pragma unroll
    for (int i = 0; i < 4; i++) {
        int k = k0 + ty + i * 8;
        int n = n0 + tx;
        size_t idx = (size_t)k * N_DIM + n;
        float wh = Wh[idx], mh = Mh[idx];
        float e2 = __expf(2.f * wh);
        float th = 1.f - 2.f / (e2 + 1.f);          // tanh(wh)
        tw[ty + i * 8][tx] = th * (1.f / (1.f + __expf(-mh)));
        tg[ty + i * 8][tx] = Gf[idx];
    }
    __syncthreads();
#pragma unroll
    for (int i = 0; i < 4; i++) {
        int n = n0 + ty + i * 8;
        int k = k0 + tx;
        Wt[(size_t)n * K_DIM + k] = f2bf(tw[tx][ty + i * 8]);
        Gt[(size_t)n * K_DIM + k] = f2bf(tg[tx][ty + i * 8]);
    }
}

// ---------------- fused GEMM: a = Xb@Wt^T, lm = Lb@Wt^T, gl = Xb@Gt^T ----------------
// out = sigmoid(gl)*a + (1-sigmoid(gl))*exp(lm)
//
// Round-8: base = r5 (best, 267us, MfmaUtil 33%; r6 32x32 reverted 324us;
// r7 2-blk/CU null 284us). Cycle audit: 5000 cy/K-step = serial SUM of MFMA
// drain (1862) + LDS service (~1400-1900) + 8 barriers -> pipes still not
// overlapping: phase read-sets were lopsided (8/4/4/0) and lgkmcnt(0) made
// every phase wait for everything.
// ONE lever: software-pipeline fragment reads one phase ahead with COUNTED
// waits (compiler-inserted lgkm(4)/lgkm(4)/lgkm(0)/none — the m97 pattern):
//   PH0: issue A23 reads;  MFMA q(mi01 x ni01) on F0 (preloaded last PH3)
//   PH1: issue B23 reads;  MFMA q(mi23 x ni01)
//   PH2: (no reads)        MFMA q(mi01 x ni23)
//   PH3: STAGE; VM12; BAR; prefetch next-step F0 (8 reads from NXT);
//        MFMA q(mi23 x ni23)
// Reads/phase = 4/4/0/8, each waited one full phase later (>=466cy slack).
// Barriers 8 -> 5 per K-step. No explicit lgkmcnt(0) (rule-18 asm-hoist
// hazard gone; compiler tracks deps exactly). sched_barrier(0) pins each
// read batch above its MFMA cluster.
// Hazards: A23 retired before PH1 MFMAs, B23 before PH2's; PH2-close BAR
// collectivizes -> STAGE into CUR safe. Prefetch reads NXT only after
// VM12 + BAR (all waves' loads for NXT landed). Ring-3, tails VM6/VM0.
// Carried: T2 XOR swizzle (linear gld_lds dest, swizzle-inverse global
// source, XOR read addr; read pattern verified bank-balanced: 8 lanes/quad).
// Ledger: SQ_LDS_BANK_CONFLICT == 2^24 exactly in all rounds -> artifact.
#define BUFE 24576            // elems per buffer (48 KB): X 8192 | L 8192 | W 4096 | G 4096

__global__ __launch_bounds__(512, 2) void gemm_fused(const ushort* __restrict__ Xb,
                                                     const ushort* __restrict__ Lb,
                                                     const ushort* __restrict__ Wt,
                                                     const ushort* __restrict__ Gt,
                                                     float* __restrict__ out) {
    extern __shared__ ushort smem[];

    const int t = threadIdx.x;          // 0..511
    const int lane = t & 63;
    const int w = t >> 6;               // 0..7
    const int wm = w >> 1;              // 0..3 (M quadrant)
    const int wn = w & 1;               // 0..1 (N half)
    const int rowA = blockIdx.y * 256;  // M tile base
    const int rowB = blockIdx.x * 128;  // N tile base

    floatx4 acca[4][4], accm[4][4], accg[4][4];
    const floatx4 z = {0.f, 0.f, 0.f, 0.f};
#pragma unroll
    for (int i = 0; i < 4; i++)
#pragma unroll
        for (int j = 0; j < 4; j++) { acca[i][j] = z; accm[i][j] = z; accg[i][j] = z; }

    // ---- staging: swizzle-inverse source coordinates -------------------------
    // dest byte d holds global (r,c) with d == (r*64 + c*16) ^ ((r&7)<<4).
    // inverse: r = 2*(d>>7) | ((d>>6)^(d>>8))&1 ; c = ((d>>4)&3) ^ (r&3).
    const int d0 = t * 16;
    const int d1 = (t + 512) * 16;
    const int sr0 = ((d0 >> 7) << 1) | (((d0 >> 6) ^ (d0 >> 8)) & 1);
    const int sc0 = ((d0 >> 4) & 3) ^ (sr0 & 3);
    const int sr1 = ((d1 >> 7) << 1) | (((d1 >> 6) ^ (d1 >> 8)) & 1);
    const int sc1 = ((d1 >> 4) & 3) ^ (sr1 & 3);
    const int ga0 = (rowA + sr0) * K_DIM + sc0 * 8;
    const int ga1 = (rowA + sr1) * K_DIM + sc1 * 8;
    const int gb0 = (rowB + sr0) * K_DIM + sc0 * 8;
    const int e0 = t * 8, e1 = (t + 512) * 8;   // linear dest (elems)

#define STAGE(sb, kk) do {                                   \
    gld_lds16(Xb + ga0 + (kk), (sb) + e0);                   \
    gld_lds16(Xb + ga1 + (kk), (sb) + e1);                   \
    gld_lds16(Lb + ga0 + (kk), (sb) + 8192 + e0);            \
    gld_lds16(Lb + ga1 + (kk), (sb) + 8192 + e1);            \
    gld_lds16(Wt + gb0 + (kk), (sb) + 16384 + e0);           \
    gld_lds16(Gt + gb0 + (kk), (sb) + 20480 + e0);           \
} while (0)

    // ---- fragment read bases (byte offsets, swizzled) ------------------------
    const int lr = lane & 15;
    const int ck = lane >> 4;
    const int rbA = (((wm * 64 + lr) * 64) + ck * 16) ^ ((lr & 7) << 4);
    const int rbB = (((wn * 64 + lr) * 64) + ck * 16) ^ ((lr & 7) << 4);
    // per-mi/ni offsets +1024B (16 rows) are in bits >=10: no swizzle overlap.

#define TRIP(MI, NI, AX, AL, BW, BG)                                                        \
    acca[MI][NI] = __builtin_amdgcn_mfma_f32_16x16x32_bf16(AX, BW, acca[MI][NI], 0, 0, 0);  \
    accm[MI][NI] = __builtin_amdgcn_mfma_f32_16x16x32_bf16(AL, BW, accm[MI][NI], 0, 0, 0);  \
    accg[MI][NI] = __builtin_amdgcn_mfma_f32_16x16x32_bf16(AX, BG, accg[MI][NI], 0, 0, 0);

#define CF()    asm volatile("" ::: "memory")
#define BAR()   do { CF(); __builtin_amdgcn_s_barrier(); CF(); } while (0)
#define SCHB()  __builtin_amdgcn_sched_barrier(0)
#define PRIO1() __builtin_amdgcn_s_setprio(1)
#define PRIO0() __builtin_amdgcn_s_setprio(0)
#define VM12()  asm volatile("s_waitcnt vmcnt(12)" ::: "memory")
#define VM6()   asm volatile("s_waitcnt vmcnt(6)" ::: "memory")
#define VM0()   asm volatile("s_waitcnt vmcnt(0)" ::: "memory")

    // F0 fragments (mi01 A + ni01 B), loaded one phase AHEAD (prev PH3).
    short8 ax0, ax1, al0, al1, bw0, bw1, bg0, bg1;

#define PREF(B) do {                                         \
    const char* pA  = (const char*)(B) + rbA;                \
    const char* pAl = (const char*)(B) + 16384 + rbA;        \
    const char* pB  = (const char*)(B) + 32768 + rbB;        \
    const char* pBg = (const char*)(B) + 40960 + rbB;        \
    ax0 = *(const short8*)(pA);                              \
    ax1 = *(const short8*)(pA + 1024);                       \
    al0 = *(const short8*)(pAl);                             \
    al1 = *(const short8*)(pAl + 1024);                      \
    bw0 = *(const short8*)(pB);                              \
    bw1 = *(const short8*)(pB + 1024);                       \
    bg0 = *(const short8*)(pBg);                             \
    bg1 = *(const short8*)(pBg + 1024);                      \
} while (0)

    // One K-step, 4 phases; reads pipelined one phase ahead of use.
#define STEP(CUR, NXT, STG, VMW, DOPF) do {                                \
    const char* bA  = (const char*)(CUR) + rbA;                            \
    const char* bAl = (const char*)(CUR) + 16384 + rbA;                    \
    const char* bB  = (const char*)(CUR) + 32768 + rbB;                    \
    const char* bBg = (const char*)(CUR) + 40960 + rbB;                    \
    /* PH0: issue A23; MFMA q(mi01 x ni01) on F0 */                        \
    short8 ax2 = *(const short8*)(bA + 2048);                              \
    short8 ax3 = *(const short8*)(bA + 3072);                              \
    short8 al2 = *(const short8*)(bAl + 2048);                             \
    short8 al3 = *(const short8*)(bAl + 3072);                             \
    SCHB(); PRIO1();                                                       \
    TRIP(0,0,ax0,al0,bw0,bg0) TRIP(0,1,ax0,al0,bw1,bg1)                    \
    TRIP(1,0,ax1,al1,bw0,bg0) TRIP(1,1,ax1,al1,bw1,bg1)                    \
    PRIO0(); BAR();                                                        \
    /* PH1: issue B23; MFMA q(mi23 x ni01) */                              \
    short8 bw2 = *(const short8*)(bB + 2048);                              \
    short8 bw3 = *(const short8*)(bB + 3072);                              \
    short8 bg2 = *(const short8*)(bBg + 2048);                             \
    short8 bg3 = *(const short8*)(bBg + 3072);                             \
    SCHB(); PRIO1();                                                       \
    TRIP(2,0,ax2,al2,bw0,bg0) TRIP(2,1,ax2,al2,bw1,bg1)                    \
    TRIP(3,0,ax3,al3,bw0,bg0) TRIP(3,1,ax3,al3,bw1,bg1)                    \
    PRIO0(); BAR();                                                        \
    /* PH2: no reads; MFMA q(mi01 x ni23) */                               \
    PRIO1();                                                               \
    TRIP(0,2,ax0,al0,bw2,bg2) TRIP(0,3,ax0,al0,bw3,bg3)                    \
    TRIP(1,2,ax1,al1,bw2,bg2) TRIP(1,3,ax1,al1,bw3,bg3)                    \
    PRIO0(); BAR();  /* all CUR reads retired collectively -> STAGE safe */ \
    /* PH3: stage; counted vm; barrier (NXT landed); prefetch F0; q11 */   \
    STG;                                                                   \
    VMW;                                                                   \
    BAR();                                                                 \
    DOPF;                                                                  \
    SCHB(); PRIO1();                                                       \
    TRIP(2,2,ax2,al2,bw2,bg2) TRIP(2,3,ax2,al2,bw3,bg3)                    \
    TRIP(3,2,ax3,al3,bw2,bg2) TRIP(3,3,ax3,al3,bw3,bg3)                    \
    PRIO0(); BAR();                                                        \
} while (0)

    ushort* pb0 = smem;
    ushort* pb1 = smem + BUFE;
    ushort* pb2 = smem + 2 * BUFE;

    // prologue: fill 3 buffers (18 loads), wait for buffer 0's 6, preload F0
    STAGE(pb0, 0);
    STAGE(pb1, 32);
    STAGE(pb2, 64);
    VM12();
    BAR();
    PREF(pb0);

    // steady state: j=0..60 stage K-step j+3 into CUR; tails 61..63 drain
#pragma unroll 1
    for (int j = 0; j <= 60; ++j) {
        const int kst = (j + 3) * 32;
        STEP(pb0, pb1, STAGE(pb0, kst), VM12(), PREF(pb1));
        ushort* tmp = pb0; pb0 = pb1; pb1 = pb2; pb2 = tmp;
    }
    STEP(pb0, pb1, ((void)0), VM6(), PREF(pb1));     // j=61
    { ushort* tmp = pb0; pb0 = pb1; pb1 = pb2; pb2 = tmp; }
    STEP(pb0, pb1, ((void)0), VM0(), PREF(pb1));     // j=62
    { ushort* tmp = pb0; pb0 = pb1; pb1 = pb2; pb2 = tmp; }
    STEP(pb0, pb1, ((void)0), ((void)0), ((void)0)); // j=63

    // ---- epilogue (verified r1/r5 layout) -----------------------------------
    const int rsub = ck << 2;
#pragma unroll
    for (int mi = 0; mi < 4; mi++)
#pragma unroll
        for (int ni = 0; ni < 4; ni++)
#pragma unroll
            for (int r = 0; r < 4; r++) {
                int row = rowA + wm * 64 + mi * 16 + rsub + r;
                int col = rowB + wn * 64 + ni * 16 + lr;
                float g = 1.f / (1.f + __expf(-accg[mi][ni][r]));
                float a = acca[mi][ni][r];
                float m = __expf(accm[mi][ni][r]);
                out[(size_t)row * N_DIM + col] = g * a + (1.f - g) * m;
            }
}

extern "C" void kernel_launch(void* const* d_in, const int* in_sizes, int n_in,
                              void* d_out, int out_size, void* d_ws, size_t ws_size,
                              hipStream_t stream) {
    const float* X  = (const float*)d_in[0];
    const float* Wh = (const float*)d_in[1];
    const float* Mh = (const float*)d_in[2];
    const float* Gf = (const float*)d_in[3];
    float* out = (float*)d_out;

    // workspace layout (bytes):
    //   Xb : B*K*2  = 33,554,432
    //   Lb : B*K*2  = 33,554,432
    //   Wt : N*K*2  =  8,388,608   (transposed: [n][k])
    //   Gt : N*K*2  =  8,388,608
    char* ws = (char*)d_ws;
    ushort* Xb = (ushort*)(ws);
    ushort* Lb = (ushort*)(ws + (size_t)B_DIM * K_DIM * 2);
    ushort* Wt = (ushort*)(ws + (size_t)B_DIM * K_DIM * 4);
    ushort* Gt = (ushort*)(ws + (size_t)B_DIM * K_DIM * 4 + (size_t)N_DIM * K_DIM * 2);

    // 144KB dynamic LDS exceeds the default per-block cap — raise it once.
    static bool attr_set = false;
    if (!attr_set) {
        hipFuncSetAttribute((const void*)gemm_fused,
                            hipFuncAttributeMaxDynamicSharedMemorySize,
                            3 * BUFE * 2);
        attr_set = true;
    }

    prep_x<<<dim3((B_DIM * K_DIM) / (256 * 4)), dim3(256), 0, stream>>>(
        (const float4*)X, Xb, Lb);

    prep_wg<<<dim3(N_DIM / 32, K_DIM / 32), dim3(32, 8), 0, stream>>>(Wh, Mh, Gf, Wt, Gt);

    // 3 buffers x 48KB = 144KB dynamic LDS
    gemm_fused<<<dim3(N_DIM / 128, B_DIM / 256), dim3(512), 3 * BUFE * 2, stream>>>(
        Xb, Lb, Wt, Gt, out);
}